// Round 4
// baseline (127722.510 us; speedup 1.0000x reference)
//
#include <hip/hip_runtime.h>

#define Bsz  512
#define FEAT 2048
#define Hd   512
#define Vd   100
#define Td   200
#define Gd   2048   // 4*H interleaved gate columns: per 16-col group [r|z|i_n|h_n]

typedef __bf16 bf16;
typedef __bf16 bf16x8 __attribute__((ext_vector_type(8)));
typedef float  f32x4  __attribute__((ext_vector_type(4)));

// Static device storage. Rewritten every launch -> deterministic across replays.
__device__ bf16  g_hbuf[Td + 1][Bsz][Hd];   // h chain: [0]=h0, [t+1]=output of step t
__device__ bf16  g_wt0[Gd][Hd];             // step-0 weights   [gatecol][k]
__device__ bf16  g_wt1[Gd][Hd];             // steps>=1 weights [gatecol][k]
__device__ float g_bias0[Gd];
__device__ float g_bias1[Gd];
__device__ bf16  g_featbf[Bsz][FEAT];
__device__ bf16  g_whpt[Hd][FEAT];          // w_hp transposed: [n][k]
__device__ bf16  g_wprojt[112][Hd];         // w_proj transposed+padded: [v][k]
__device__ float g_gi0[3 * Hd];             // embed[SOS] @ w_ih.T + b_ih
__device__ unsigned g_flags[8][32];         // [rowgroup][colgroup] L3-scope phase flags (slow path + publish)
__device__ unsigned g_bar[8][32];           // [rowgroup][colgroup] L2-scope counters (fast path)
__device__ unsigned g_xcd[256];             // published XCC_ID per block

// ---------- device-coherent (L3, sc0 sc1) helpers — slow path ----------
template <int OFF>
__device__ __forceinline__ bf16x8 ld_b16x8_cohere(const void* p) {
  bf16x8 r;
  asm volatile("global_load_dwordx4 %0, %1, off offset:%2 sc0 sc1"
               : "=&v"(r) : "v"(p), "i"(OFF) : "memory");
  return r;
}
template <int OFF>
__device__ __forceinline__ void st_u16_cohere(void* p, unsigned short v) {
  asm volatile("global_store_short %0, %1, off offset:%2 sc0 sc1"
               :: "v"(p), "v"(v), "i"(OFF) : "memory");
}
__device__ __forceinline__ void st_u32_cohere(void* p, unsigned v) {
  asm volatile("global_store_dword %0, %1, off sc0 sc1" :: "v"(p), "v"(v) : "memory");
}
__device__ __forceinline__ unsigned ld_u32_cohere(const void* p) {
  unsigned r;
  asm volatile("global_load_dword %0, %1, off sc0 sc1\n\ts_waitcnt vmcnt(0)"
               : "=&v"(r) : "v"(p) : "memory");
  return r;
}
// ---------- XCD-scope (L2) helpers — fast path ----------
__device__ __forceinline__ unsigned ld_u32_sc0(const unsigned* p) {  // L1-bypass, L2-fresh
  unsigned r;
  asm volatile("global_load_dword %0, %1, off sc0\n\ts_waitcnt vmcnt(0)"
               : "=&v"(r) : "v"(p) : "memory");
  return r;
}
__device__ __forceinline__ unsigned atomic_rd_l2(unsigned* p) {      // RMW at L2: L1-proof read
  unsigned r;
  asm volatile("global_atomic_add %0, %1, %2, off sc0\n\ts_waitcnt vmcnt(0)"
               : "=&v"(r) : "v"(p), "v"(0u) : "memory");
  return r;
}
__device__ __forceinline__ void atomic_inc_l2(unsigned* p) {         // no-return add at L2
  asm volatile("global_atomic_add %0, %1, off" :: "v"(p), "v"(1u) : "memory");
}
__device__ __forceinline__ void wait_vm0() { asm volatile("s_waitcnt vmcnt(0)" ::: "memory"); }
__device__ __forceinline__ void wait_vm8() { asm volatile("s_waitcnt vmcnt(8)" ::: "memory"); }

#define LDA16(arr, base) do {                                                   \
  arr[0]  = ld_b16x8_cohere<0>(base);   arr[1]  = ld_b16x8_cohere<64>(base);    \
  arr[2]  = ld_b16x8_cohere<128>(base); arr[3]  = ld_b16x8_cohere<192>(base);   \
  arr[4]  = ld_b16x8_cohere<256>(base); arr[5]  = ld_b16x8_cohere<320>(base);   \
  arr[6]  = ld_b16x8_cohere<384>(base); arr[7]  = ld_b16x8_cohere<448>(base);   \
  arr[8]  = ld_b16x8_cohere<512>(base); arr[9]  = ld_b16x8_cohere<576>(base);   \
  arr[10] = ld_b16x8_cohere<640>(base); arr[11] = ld_b16x8_cohere<704>(base);   \
  arr[12] = ld_b16x8_cohere<768>(base); arr[13] = ld_b16x8_cohere<832>(base);   \
  arr[14] = ld_b16x8_cohere<896>(base); arr[15] = ld_b16x8_cohere<960>(base);   \
} while (0)

__device__ __forceinline__ float sigmoidf_(float x) {
  x = fminf(fmaxf(x, -30.f), 30.f);
  return 1.f / (1.f + __expf(-x));
}
__device__ __forceinline__ float tanhf_(float x) {
  x = fminf(fmaxf(x, -15.f), 15.f);
  float e = __expf(2.f * x);
  return (e - 1.f) / (e + 1.f);
}

// Slow-path / publish barrier: device scope through L3 (placement-independent).
__device__ __forceinline__ void group_barrier(int rg, int cg, unsigned phase) {
  wait_vm0();
  __syncthreads();
  if (threadIdx.x == 0) st_u32_cohere(&g_flags[rg][cg], phase);
  if (threadIdx.x < 64) {
    const unsigned* fp = &g_flags[rg][threadIdx.x & 31];
    while (ld_u32_cohere(fp) < phase) __builtin_amdgcn_s_sleep(1);
  }
  __syncthreads();
}

// Fast-path barrier: flags RMW'd at the shared XCD L2. Only valid when all 32
// blocks of rg verified co-resident on one XCD. Escalates polls to atomic
// reads after 8192 spins as insurance against sc0 semantics surprises.
__device__ __forceinline__ void barrier_fast(int rg, int cg, unsigned phase) {
  wait_vm0();          // this wave's h stores are in L2
  __syncthreads();     // all 4 waves drained
  if (threadIdx.x == 0) atomic_inc_l2(&g_bar[rg][cg]);
  if (threadIdx.x < 64) {
    unsigned* fp = &g_bar[rg][threadIdx.x & 31];
    unsigned v = ld_u32_sc0(fp);
    int it = 0;
    while (v < phase) {
      ++it;
      v = (it > 8192) ? atomic_rd_l2(fp) : ld_u32_sc0(fp);
    }
  }
  __syncthreads();
}

// ---------- prep kernels ----------

__global__ void k_conv_feat(const float* feat) {
  int i = blockIdx.x * 256 + threadIdx.x;
  if (i < Bsz * FEAT) ((bf16*)g_featbf)[i] = (bf16)feat[i];
  if (blockIdx.x == 0) {  // reset barrier/publish state each replay
    ((unsigned*)g_flags)[threadIdx.x] = 0u;
    ((unsigned*)g_bar)[threadIdx.x] = 0u;
    g_xcd[threadIdx.x] = 0xffffffffu;
  }
}

__global__ void k_gi0(const float* embed, const float* w_ih, const float* b_ih) {
  int j = blockIdx.x;
  const float* wr = w_ih + (size_t)j * Hd;
  float s = 0.f;
  for (int k = threadIdx.x; k < Hd; k += 64) s += embed[k] * wr[k];
#pragma unroll
  for (int off = 32; off > 0; off >>= 1) s += __shfl_down(s, off);
  if (threadIdx.x == 0) g_gi0[j] = s + b_ih[j];
}

// gate col c: group g=c/64 (16 h-cols), f=(c>>4)&3 in {r,z,i_n,h_n}, j = g*16 + (c&15)
__global__ void k_build_wt1(const float* w_ih, const float* w_hh,
                            const float* b_ih, const float* b_hh) {
  int c = blockIdx.x;
  int j = (c >> 6) * 16 + (c & 15);
  int f = (c >> 4) & 3;
  const float* s1 = nullptr; const float* s2 = nullptr; float bias;
  if (f == 0)      { s1 = w_ih + (size_t)j * Hd;            s2 = w_hh + (size_t)j * Hd;            bias = b_ih[j] + b_hh[j]; }
  else if (f == 1) { s1 = w_ih + (size_t)(Hd + j) * Hd;     s2 = w_hh + (size_t)(Hd + j) * Hd;     bias = b_ih[Hd + j] + b_hh[Hd + j]; }
  else if (f == 2) { s1 = w_ih + (size_t)(2 * Hd + j) * Hd;                                        bias = b_ih[2 * Hd + j]; }
  else             { s1 = w_hh + (size_t)(2 * Hd + j) * Hd;                                        bias = b_hh[2 * Hd + j]; }
  for (int k = threadIdx.x; k < Hd; k += 256) {
    float v = s1[k] + (s2 ? s2[k] : 0.f);
    g_wt1[c][k] = (bf16)v;
  }
  if (threadIdx.x == 0) g_bias1[c] = bias;
}

__global__ void k_build_wt0(const float* w_hh, const float* b_hh) {
  int c = blockIdx.x;
  int j = (c >> 6) * 16 + (c & 15);
  int f = (c >> 4) & 3;
  const float* s1 = nullptr; float bias;
  if (f == 0)      { s1 = w_hh + (size_t)j * Hd;            bias = g_gi0[j] + b_hh[j]; }
  else if (f == 1) { s1 = w_hh + (size_t)(Hd + j) * Hd;     bias = g_gi0[Hd + j] + b_hh[Hd + j]; }
  else if (f == 2) {                                        bias = g_gi0[2 * Hd + j]; }
  else             { s1 = w_hh + (size_t)(2 * Hd + j) * Hd; bias = b_hh[2 * Hd + j]; }
  for (int k = threadIdx.x; k < Hd; k += 256)
    g_wt0[c][k] = (bf16)(s1 ? s1[k] : 0.f);
  if (threadIdx.x == 0) g_bias0[c] = bias;
}

__global__ void k_build_whpt(const float* w_hp) {
  int n = blockIdx.x;
  for (int k = threadIdx.x; k < FEAT; k += 256)
    g_whpt[n][k] = (bf16)w_hp[(size_t)k * Hd + n];
}

__global__ void k_build_wprojt(const float* w_proj) {
  int v = blockIdx.x;  // 0..111
  for (int k = threadIdx.x; k < Hd; k += 256)
    g_wprojt[v][k] = (bf16)(v < Vd ? w_proj[(size_t)k * Vd + v] : 0.f);
}

// ---------- persistent kernel: h0 + all 200 GRU steps ----------
// 256 blocks (1/CU), 256 threads. rg=bid&7: 64-row batch group (same XCD under
// round-robin dispatch); cg=bid>>3: 16 h-col group. Steps>=1 weights persist in
// VGPR/AGPR. Runtime XCC_ID check selects L2-scope (fast) or L3-scope (slow)
// h exchange; correctness never depends on placement (G16).
__global__ __launch_bounds__(256, 1) void k_gru_seq(const float* b_hp) {
  const int bid = blockIdx.x;
  const int rg = bid & 7;
  const int cg = bid >> 3;
  const int w = threadIdx.x >> 6, l = threadIdx.x & 63;
  const int m = l & 15;
  const int ksub = (l >> 4) * 8;
  const int colb = cg * 64;
  const int arow = rg * 64 + w * 16 + m;
  const int orow = rg * 64 + w * 16 + (l >> 4) * 4;
  const int hcol = cg * 16 + m;
  __shared__ int s_fast;

  // persistent B-fragments for steps >= 1 (4 gates x 16 k-chunks)
  bf16x8 Bw[64];
#pragma unroll
  for (int f = 0; f < 4; f++)
#pragma unroll
    for (int k0 = 0; k0 < 16; k0++)
      Bw[f * 16 + k0] = *(const bf16x8*)&g_wt1[colb + f * 16 + m][k0 * 32 + ksub];

  float b0v[4], b1v[4];
#pragma unroll
  for (int f = 0; f < 4; f++) {
    b0v[f] = g_bias0[colb + f * 16 + m];
    b1v[f] = g_bias1[colb + f * 16 + m];
  }

  // ---- publish XCC_ID, then decide fast/slow per row group ----
  unsigned xcc;
  asm volatile("s_getreg_b32 %0, hwreg(HW_REG_XCC_ID)" : "=s"(xcc));
  if (threadIdx.x == 0) st_u32_cohere(&g_xcd[bid], xcc);
  group_barrier(rg, cg, 1u);  // publish complete (L3 scope)
  if (threadIdx.x < 64) {
    unsigned peer = ld_u32_cohere(&g_xcd[rg + 8 * (threadIdx.x & 31)]);
    unsigned long long bal = __ballot(peer == xcc);
    if (threadIdx.x == 0) s_fast = (bal == ~0ull) ? 1 : 0;
  }
  __syncthreads();
  const bool fast = (s_fast != 0);

  // ---- h0 = feat @ w_hp + b_hp ----
  float hcarry[4];
  {
    f32x4 acc = {0.f, 0.f, 0.f, 0.f};
#pragma unroll 4
    for (int k0 = 0; k0 < FEAT; k0 += 32) {
      bf16x8 a = *(const bf16x8*)&g_featbf[arow][k0 + ksub];
      bf16x8 b = *(const bf16x8*)&g_whpt[hcol][k0 + ksub];
      acc = __builtin_amdgcn_mfma_f32_16x16x32_bf16(a, b, acc, 0, 0, 0);
    }
    float bhp = b_hp[hcol];
    bf16* pb = &g_hbuf[0][orow][hcol];
    unsigned short us[4];
#pragma unroll
    for (int i = 0; i < 4; i++) {
      bf16 hv = (bf16)(acc[i] + bhp);
      hcarry[i] = (float)hv;
      us[i] = __builtin_bit_cast(unsigned short, hv);
    }
    if (fast) {
#pragma unroll
      for (int i = 0; i < 4; i++) pb[i * Hd] = __builtin_bit_cast(bf16, us[i]);
    } else {
      char* pc = (char*)pb;
      st_u16_cohere<0>(pc, us[0]);    st_u16_cohere<1024>(pc, us[1]);
      st_u16_cohere<2048>(pc, us[2]); st_u16_cohere<3072>(pc, us[3]);
    }
  }

  if (fast) {
    barrier_fast(rg, cg, 1u);  // h0 complete (L2 scope)
    for (int t = 0; t < Td; t++) {
      bf16x8 a[16];
      const bf16* Ap = &g_hbuf[t][arow][ksub];
#pragma unroll
      for (int k0 = 0; k0 < 16; k0++) a[k0] = *(const bf16x8*)(Ap + k0 * 32);

      f32x4 acc[4];
#pragma unroll
      for (int f = 0; f < 4; f++) {
        float bv = (t == 0) ? b0v[f] : b1v[f];
        acc[f] = (f32x4){bv, bv, bv, bv};
      }
      if (t == 0) {
#pragma unroll
        for (int k0 = 0; k0 < 16; k0++)
#pragma unroll
          for (int f = 0; f < 4; f++) {
            bf16x8 b = *(const bf16x8*)&g_wt0[colb + f * 16 + m][k0 * 32 + ksub];
            acc[f] = __builtin_amdgcn_mfma_f32_16x16x32_bf16(a[k0], b, acc[f], 0, 0, 0);
          }
      } else {
#pragma unroll
        for (int k0 = 0; k0 < 16; k0++)
#pragma unroll
          for (int f = 0; f < 4; f++)
            acc[f] = __builtin_amdgcn_mfma_f32_16x16x32_bf16(a[k0], Bw[f * 16 + k0], acc[f], 0, 0, 0);
      }

      bf16* pb = &g_hbuf[t + 1][orow][hcol];
#pragma unroll
      for (int i = 0; i < 4; i++) {
        float r = sigmoidf_(acc[0][i]);
        float z = sigmoidf_(acc[1][i]);
        float n = tanhf_(acc[2][i] + r * acc[3][i]);
        float hn = (1.f - z) * n + z * hcarry[i];
        bf16 hv = (bf16)hn;
        hcarry[i] = (float)hv;
        pb[i * Hd] = hv;
      }
      if (t < Td - 1) barrier_fast(rg, cg, (unsigned)(t + 2));
    }
  } else {
    group_barrier(rg, cg, 2u);  // h0 complete (L3 scope)
    for (int t = 0; t < Td; t++) {
      bf16x8 a[16];
      const char* Ap = (const char*)&g_hbuf[t][arow][ksub];
      LDA16(a, Ap);

      f32x4 acc[4];
#pragma unroll
      for (int f = 0; f < 4; f++) {
        float bv = (t == 0) ? b0v[f] : b1v[f];
        acc[f] = (f32x4){bv, bv, bv, bv};
      }
      if (t == 0) {
        wait_vm0(); __builtin_amdgcn_sched_barrier(0);
#pragma unroll
        for (int k0 = 0; k0 < 16; k0++)
#pragma unroll
          for (int f = 0; f < 4; f++) {
            bf16x8 b = *(const bf16x8*)&g_wt0[colb + f * 16 + m][k0 * 32 + ksub];
            acc[f] = __builtin_amdgcn_mfma_f32_16x16x32_bf16(a[k0], b, acc[f], 0, 0, 0);
          }
      } else {
        wait_vm8(); __builtin_amdgcn_sched_barrier(0);
#pragma unroll
        for (int k0 = 0; k0 < 8; k0++)
#pragma unroll
          for (int f = 0; f < 4; f++)
            acc[f] = __builtin_amdgcn_mfma_f32_16x16x32_bf16(a[k0], Bw[f * 16 + k0], acc[f], 0, 0, 0);
        wait_vm0(); __builtin_amdgcn_sched_barrier(0);
#pragma unroll
        for (int k0 = 8; k0 < 16; k0++)
#pragma unroll
          for (int f = 0; f < 4; f++)
            acc[f] = __builtin_amdgcn_mfma_f32_16x16x32_bf16(a[k0], Bw[f * 16 + k0], acc[f], 0, 0, 0);
      }

      char* pb = (char*)&g_hbuf[t + 1][orow][hcol];
      unsigned short us[4];
#pragma unroll
      for (int i = 0; i < 4; i++) {
        float r = sigmoidf_(acc[0][i]);
        float z = sigmoidf_(acc[1][i]);
        float n = tanhf_(acc[2][i] + r * acc[3][i]);
        float hn = (1.f - z) * n + z * hcarry[i];
        bf16 hv = (bf16)hn;
        hcarry[i] = (float)hv;
        us[i] = __builtin_bit_cast(unsigned short, hv);
      }
      st_u16_cohere<0>(pb, us[0]);    st_u16_cohere<1024>(pb, us[1]);
      st_u16_cohere<2048>(pb, us[2]); st_u16_cohere<3072>(pb, us[3]);

      if (t < Td - 1) group_barrier(rg, cg, (unsigned)(t + 3));
    }
  }
  wait_vm0();  // h[200] stores complete before kernel end (end-of-kernel release handles visibility)
}

// ---------- projection: out[b][v][t] = sum_k h[t+1][b][k] * w_proj[k][v] + b_proj[v] ----------
// 256-thread blocks, grid (512,4): wave w handles t-tile by*4+w. Plain cached
// loads (inter-kernel visibility guaranteed by kernel-boundary coherence).
__global__ __launch_bounds__(256) void k_proj(const float* b_proj, float* out) {
  int b = blockIdx.x;
  int w = threadIdx.x >> 6, l = threadIdx.x & 63;
  int tt = blockIdx.y * 4 + w;
  if (tt > 12) return;
  int m = l & 15, ksub = (l >> 4) * 8;
  int tcol = tt * 16 + m;
  int trow = (tcol < Td ? tcol : Td - 1) + 1;  // clamp pad cols (masked on store)

  f32x4 acc[7];
#pragma unroll
  for (int f = 0; f < 7; f++)
#pragma unroll
    for (int i = 0; i < 4; i++) {
      int v = f * 16 + (l >> 4) * 4 + i;
      acc[f][i] = (v < Vd) ? b_proj[v] : 0.f;
    }

  bf16x8 bb[16];
  const bf16* Bp = &g_hbuf[trow][b][ksub];
#pragma unroll
  for (int k0 = 0; k0 < 16; k0++) bb[k0] = *(const bf16x8*)(Bp + k0 * 32);

#pragma unroll
  for (int k0 = 0; k0 < 16; k0++)
#pragma unroll
    for (int f = 0; f < 7; f++) {
      bf16x8 afrag = *(const bf16x8*)&g_wprojt[f * 16 + m][k0 * 32 + ksub];
      acc[f] = __builtin_amdgcn_mfma_f32_16x16x32_bf16(afrag, bb[k0], acc[f], 0, 0, 0);
    }

  if (tcol < Td) {
#pragma unroll
    for (int f = 0; f < 7; f++)
#pragma unroll
      for (int i = 0; i < 4; i++) {
        int v = f * 16 + (l >> 4) * 4 + i;
        if (v < Vd) out[((size_t)b * Vd + v) * Td + tcol] = acc[f][i];
      }
  }
}

// ---------- launch ----------
extern "C" void kernel_launch(void* const* d_in, const int* in_sizes, int n_in,
                              void* d_out, int out_size, void* d_ws, size_t ws_size,
                              hipStream_t stream) {
  const float* feat   = (const float*)d_in[0];
  const float* w_hp   = (const float*)d_in[1];
  const float* b_hp   = (const float*)d_in[2];
  const float* embed  = (const float*)d_in[3];
  const float* w_ih   = (const float*)d_in[4];
  const float* w_hh   = (const float*)d_in[5];
  const float* b_ih   = (const float*)d_in[6];
  const float* b_hh   = (const float*)d_in[7];
  const float* w_proj = (const float*)d_in[8];
  const float* b_proj = (const float*)d_in[9];
  float* out = (float*)d_out;

  hipLaunchKernelGGL(k_conv_feat, dim3((Bsz * FEAT) / 256), dim3(256), 0, stream, feat);
  hipLaunchKernelGGL(k_gi0, dim3(3 * Hd), dim3(64), 0, stream, embed, w_ih, b_ih);
  hipLaunchKernelGGL(k_build_wt1, dim3(Gd), dim3(256), 0, stream, w_ih, w_hh, b_ih, b_hh);
  hipLaunchKernelGGL(k_build_wt0, dim3(Gd), dim3(256), 0, stream, w_hh, b_hh);
  hipLaunchKernelGGL(k_build_whpt, dim3(Hd), dim3(256), 0, stream, w_hp);
  hipLaunchKernelGGL(k_build_wprojt, dim3(112), dim3(256), 0, stream, w_proj);
  hipLaunchKernelGGL(k_gru_seq, dim3(256), dim3(256), 0, stream, b_hp);
  hipLaunchKernelGGL(k_proj, dim3(Bsz, 4), dim3(256), 0, stream, b_proj, out);
}

// Round 5
// 1198.391 us; speedup vs baseline: 106.5783x; 106.5783x over previous
//
#include <hip/hip_runtime.h>

#define Bsz  512
#define FEAT 2048
#define Hd   512
#define Vd   100
#define Td   200
#define Gd   2048   // 4*H interleaved gate columns: per 16-col group [r|z|i_n|h_n]

typedef __bf16 bf16;
typedef __bf16 bf16x8 __attribute__((ext_vector_type(8)));
typedef float  f32x4  __attribute__((ext_vector_type(4)));

// Static device storage. Rewritten every launch -> deterministic across replays.
__device__ bf16  g_hbuf[Td + 1][Bsz][Hd];   // h chain: [0]=h0, [t+1]=output of step t
__device__ bf16  g_wt0[Gd][Hd];             // step-0 weights   [gatecol][k]
__device__ bf16  g_wt1[Gd][Hd];             // steps>=1 weights [gatecol][k]
__device__ float g_bias0[Gd];
__device__ float g_bias1[Gd];
__device__ bf16  g_featbf[Bsz][FEAT];
__device__ bf16  g_whpt[Hd][FEAT];          // w_hp transposed: [n][k]
__device__ bf16  g_wprojt[112][Hd];         // w_proj transposed+padded: [v][k]
__device__ float g_gi0[3 * Hd];             // embed[SOS] @ w_ih.T + b_ih
__device__ unsigned g_flags[8][32];         // [rowgroup][colgroup] L3-scope phase flags (slow path + publish)
__device__ unsigned g_bar[8][32];           // [rowgroup][colgroup] L2-scope counters (fast path)
__device__ unsigned g_xcd[256];             // published XCC_ID per block

// ---------- device-coherent (L3, sc0 sc1) helpers — slow path ----------
template <int OFF>
__device__ __forceinline__ bf16x8 ld_b16x8_cohere(const void* p) {
  bf16x8 r;
  asm volatile("global_load_dwordx4 %0, %1, off offset:%2 sc0 sc1"
               : "=&v"(r) : "v"(p), "i"(OFF) : "memory");
  return r;
}
template <int OFF>
__device__ __forceinline__ void st_u16_cohere(void* p, unsigned short v) {
  asm volatile("global_store_short %0, %1, off offset:%2 sc0 sc1"
               :: "v"(p), "v"(v), "i"(OFF) : "memory");
}
__device__ __forceinline__ void st_u32_cohere(void* p, unsigned v) {
  asm volatile("global_store_dword %0, %1, off sc0 sc1" :: "v"(p), "v"(v) : "memory");
}
__device__ __forceinline__ unsigned ld_u32_cohere(const void* p) {
  unsigned r;
  asm volatile("global_load_dword %0, %1, off sc0 sc1\n\ts_waitcnt vmcnt(0)"
               : "=&v"(r) : "v"(p) : "memory");
  return r;
}
// ---------- L2-atomic helpers — fast path ----------
// LESSON (round 4): plain or sc0-only loads can spin forever on L1-stale flag
// lines; only an atomic RMW is architecturally guaranteed to read L2.
__device__ __forceinline__ unsigned atomic_rd_l2(unsigned* p) {      // RMW at L2: L1-proof read
  unsigned r;
  asm volatile("global_atomic_add %0, %1, %2, off sc0\n\ts_waitcnt vmcnt(0)"
               : "=&v"(r) : "v"(p), "v"(0u) : "memory");
  return r;
}
__device__ __forceinline__ void atomic_inc_l2(unsigned* p) {         // no-return add at L2
  asm volatile("global_atomic_add %0, %1, off" :: "v"(p), "v"(1u) : "memory");
}
__device__ __forceinline__ void wait_vm0() { asm volatile("s_waitcnt vmcnt(0)" ::: "memory"); }
__device__ __forceinline__ void wait_vm8() { asm volatile("s_waitcnt vmcnt(8)" ::: "memory"); }

#define LDA16(arr, base) do {                                                   \
  arr[0]  = ld_b16x8_cohere<0>(base);   arr[1]  = ld_b16x8_cohere<64>(base);    \
  arr[2]  = ld_b16x8_cohere<128>(base); arr[3]  = ld_b16x8_cohere<192>(base);   \
  arr[4]  = ld_b16x8_cohere<256>(base); arr[5]  = ld_b16x8_cohere<320>(base);   \
  arr[6]  = ld_b16x8_cohere<384>(base); arr[7]  = ld_b16x8_cohere<448>(base);   \
  arr[8]  = ld_b16x8_cohere<512>(base); arr[9]  = ld_b16x8_cohere<576>(base);   \
  arr[10] = ld_b16x8_cohere<640>(base); arr[11] = ld_b16x8_cohere<704>(base);   \
  arr[12] = ld_b16x8_cohere<768>(base); arr[13] = ld_b16x8_cohere<832>(base);   \
  arr[14] = ld_b16x8_cohere<896>(base); arr[15] = ld_b16x8_cohere<960>(base);   \
} while (0)

__device__ __forceinline__ float sigmoidf_(float x) {
  x = fminf(fmaxf(x, -30.f), 30.f);
  return 1.f / (1.f + __expf(-x));
}
__device__ __forceinline__ float tanhf_(float x) {
  x = fminf(fmaxf(x, -15.f), 15.f);
  float e = __expf(2.f * x);
  return (e - 1.f) / (e + 1.f);
}

// Slow-path / publish barrier: device scope through L3 (placement-independent).
__device__ __forceinline__ void group_barrier(int rg, int cg, unsigned phase) {
  wait_vm0();
  __syncthreads();
  if (threadIdx.x == 0) st_u32_cohere(&g_flags[rg][cg], phase);
  if (threadIdx.x < 64) {
    const unsigned* fp = &g_flags[rg][threadIdx.x & 31];
    while (ld_u32_cohere(fp) < phase) __builtin_amdgcn_s_sleep(1);
  }
  __syncthreads();
}

// Fast-path barrier: per-block counters at the shared XCD L2. Valid only when
// all 32 blocks of rg are verified co-resident on one XCD. Both the increment
// and every poll are atomic RMWs (L1-proof).
__device__ __forceinline__ void barrier_fast(int rg, int cg, unsigned phase) {
  wait_vm0();          // this wave's h stores have reached L2 (point of coherence)
  __syncthreads();     // all 4 waves drained
  if (threadIdx.x == 0) atomic_inc_l2(&g_bar[rg][cg]);
  if (threadIdx.x < 32) {
    unsigned* fp = &g_bar[rg][threadIdx.x];
    while (atomic_rd_l2(fp) < phase) { }
  }
  __syncthreads();
}

// ---------- prep kernels ----------

__global__ void k_conv_feat(const float* feat) {
  int i = blockIdx.x * 256 + threadIdx.x;
  if (i < Bsz * FEAT) ((bf16*)g_featbf)[i] = (bf16)feat[i];
  if (blockIdx.x == 0) {  // reset barrier/publish state each replay
    ((unsigned*)g_flags)[threadIdx.x] = 0u;
    ((unsigned*)g_bar)[threadIdx.x] = 0u;
    g_xcd[threadIdx.x] = 0xffffffffu;
  }
}

__global__ void k_gi0(const float* embed, const float* w_ih, const float* b_ih) {
  int j = blockIdx.x;
  const float* wr = w_ih + (size_t)j * Hd;
  float s = 0.f;
  for (int k = threadIdx.x; k < Hd; k += 64) s += embed[k] * wr[k];
#pragma unroll
  for (int off = 32; off > 0; off >>= 1) s += __shfl_down(s, off);
  if (threadIdx.x == 0) g_gi0[j] = s + b_ih[j];
}

// gate col c: group g=c/64 (16 h-cols), f=(c>>4)&3 in {r,z,i_n,h_n}, j = g*16 + (c&15)
__global__ void k_build_wt1(const float* w_ih, const float* w_hh,
                            const float* b_ih, const float* b_hh) {
  int c = blockIdx.x;
  int j = (c >> 6) * 16 + (c & 15);
  int f = (c >> 4) & 3;
  const float* s1 = nullptr; const float* s2 = nullptr; float bias;
  if (f == 0)      { s1 = w_ih + (size_t)j * Hd;            s2 = w_hh + (size_t)j * Hd;            bias = b_ih[j] + b_hh[j]; }
  else if (f == 1) { s1 = w_ih + (size_t)(Hd + j) * Hd;     s2 = w_hh + (size_t)(Hd + j) * Hd;     bias = b_ih[Hd + j] + b_hh[Hd + j]; }
  else if (f == 2) { s1 = w_ih + (size_t)(2 * Hd + j) * Hd;                                        bias = b_ih[2 * Hd + j]; }
  else             { s1 = w_hh + (size_t)(2 * Hd + j) * Hd;                                        bias = b_hh[2 * Hd + j]; }
  for (int k = threadIdx.x; k < Hd; k += 256) {
    float v = s1[k] + (s2 ? s2[k] : 0.f);
    g_wt1[c][k] = (bf16)v;
  }
  if (threadIdx.x == 0) g_bias1[c] = bias;
}

__global__ void k_build_wt0(const float* w_hh, const float* b_hh) {
  int c = blockIdx.x;
  int j = (c >> 6) * 16 + (c & 15);
  int f = (c >> 4) & 3;
  const float* s1 = nullptr; float bias;
  if (f == 0)      { s1 = w_hh + (size_t)j * Hd;            bias = g_gi0[j] + b_hh[j]; }
  else if (f == 1) { s1 = w_hh + (size_t)(Hd + j) * Hd;     bias = g_gi0[Hd + j] + b_hh[Hd + j]; }
  else if (f == 2) {                                        bias = g_gi0[2 * Hd + j]; }
  else             { s1 = w_hh + (size_t)(2 * Hd + j) * Hd; bias = b_hh[2 * Hd + j]; }
  for (int k = threadIdx.x; k < Hd; k += 256)
    g_wt0[c][k] = (bf16)(s1 ? s1[k] : 0.f);
  if (threadIdx.x == 0) g_bias0[c] = bias;
}

__global__ void k_build_whpt(const float* w_hp) {
  int n = blockIdx.x;
  for (int k = threadIdx.x; k < FEAT; k += 256)
    g_whpt[n][k] = (bf16)w_hp[(size_t)k * Hd + n];
}

__global__ void k_build_wprojt(const float* w_proj) {
  int v = blockIdx.x;  // 0..111
  for (int k = threadIdx.x; k < Hd; k += 256)
    g_wprojt[v][k] = (bf16)(v < Vd ? w_proj[(size_t)k * Vd + v] : 0.f);
}

// ---------- persistent kernel: h0 + all 200 GRU steps ----------
// 256 blocks (1/CU), 256 threads. rg=bid&7: 64-row batch group (same XCD under
// round-robin dispatch); cg=bid>>3: 16 h-col group. Steps>=1 weights persist in
// VGPR/AGPR. Runtime XCC_ID check selects L2-scope (fast) or L3-scope (slow)
// h exchange; correctness never depends on placement (G16).
__global__ __launch_bounds__(256, 1) void k_gru_seq(const float* b_hp) {
  const int bid = blockIdx.x;
  const int rg = bid & 7;
  const int cg = bid >> 3;
  const int w = threadIdx.x >> 6, l = threadIdx.x & 63;
  const int m = l & 15;
  const int ksub = (l >> 4) * 8;
  const int colb = cg * 64;
  const int arow = rg * 64 + w * 16 + m;
  const int orow = rg * 64 + w * 16 + (l >> 4) * 4;
  const int hcol = cg * 16 + m;
  __shared__ int s_fast;

  // persistent B-fragments for steps >= 1 (4 gates x 16 k-chunks)
  bf16x8 Bw[64];
#pragma unroll
  for (int f = 0; f < 4; f++)
#pragma unroll
    for (int k0 = 0; k0 < 16; k0++)
      Bw[f * 16 + k0] = *(const bf16x8*)&g_wt1[colb + f * 16 + m][k0 * 32 + ksub];

  float b0v[4], b1v[4];
#pragma unroll
  for (int f = 0; f < 4; f++) {
    b0v[f] = g_bias0[colb + f * 16 + m];
    b1v[f] = g_bias1[colb + f * 16 + m];
  }

  // ---- publish XCC_ID, then decide fast/slow per row group ----
  unsigned xcc;
  asm volatile("s_getreg_b32 %0, hwreg(HW_REG_XCC_ID)" : "=s"(xcc));
  if (threadIdx.x == 0) st_u32_cohere(&g_xcd[bid], xcc);
  group_barrier(rg, cg, 1u);  // publish complete (L3 scope)
  if (threadIdx.x < 64) {
    unsigned peer = ld_u32_cohere(&g_xcd[rg + 8 * (threadIdx.x & 31)]);
    unsigned long long bal = __ballot(peer == xcc);
    if (threadIdx.x == 0) s_fast = (bal == ~0ull) ? 1 : 0;
  }
  __syncthreads();
  const bool fast = (s_fast != 0);

  // ---- h0 = feat @ w_hp + b_hp ----
  float hcarry[4];
  {
    f32x4 acc = {0.f, 0.f, 0.f, 0.f};
#pragma unroll 4
    for (int k0 = 0; k0 < FEAT; k0 += 32) {
      bf16x8 a = *(const bf16x8*)&g_featbf[arow][k0 + ksub];
      bf16x8 b = *(const bf16x8*)&g_whpt[hcol][k0 + ksub];
      acc = __builtin_amdgcn_mfma_f32_16x16x32_bf16(a, b, acc, 0, 0, 0);
    }
    float bhp = b_hp[hcol];
    bf16* pb = &g_hbuf[0][orow][hcol];
    unsigned short us[4];
#pragma unroll
    for (int i = 0; i < 4; i++) {
      bf16 hv = (bf16)(acc[i] + bhp);
      hcarry[i] = (float)hv;
      us[i] = __builtin_bit_cast(unsigned short, hv);
    }
    if (fast) {
#pragma unroll
      for (int i = 0; i < 4; i++) pb[i * Hd] = __builtin_bit_cast(bf16, us[i]);
    } else {
      char* pc = (char*)pb;
      st_u16_cohere<0>(pc, us[0]);    st_u16_cohere<1024>(pc, us[1]);
      st_u16_cohere<2048>(pc, us[2]); st_u16_cohere<3072>(pc, us[3]);
    }
  }

  if (fast) {
    barrier_fast(rg, cg, 1u);  // h0 complete (L2 scope)
    for (int t = 0; t < Td; t++) {
      bf16x8 a[16];
      const bf16* Ap = &g_hbuf[t][arow][ksub];
#pragma unroll
      for (int k0 = 0; k0 < 16; k0++) a[k0] = *(const bf16x8*)(Ap + k0 * 32);

      f32x4 acc[4];
#pragma unroll
      for (int f = 0; f < 4; f++) {
        float bv = (t == 0) ? b0v[f] : b1v[f];
        acc[f] = (f32x4){bv, bv, bv, bv};
      }
      if (t == 0) {
#pragma unroll
        for (int k0 = 0; k0 < 16; k0++)
#pragma unroll
          for (int f = 0; f < 4; f++) {
            bf16x8 b = *(const bf16x8*)&g_wt0[colb + f * 16 + m][k0 * 32 + ksub];
            acc[f] = __builtin_amdgcn_mfma_f32_16x16x32_bf16(a[k0], b, acc[f], 0, 0, 0);
          }
      } else {
#pragma unroll
        for (int k0 = 0; k0 < 16; k0++)
#pragma unroll
          for (int f = 0; f < 4; f++)
            acc[f] = __builtin_amdgcn_mfma_f32_16x16x32_bf16(a[k0], Bw[f * 16 + k0], acc[f], 0, 0, 0);
      }

      bf16* pb = &g_hbuf[t + 1][orow][hcol];
#pragma unroll
      for (int i = 0; i < 4; i++) {
        float r = sigmoidf_(acc[0][i]);
        float z = sigmoidf_(acc[1][i]);
        float n = tanhf_(acc[2][i] + r * acc[3][i]);
        float hn = (1.f - z) * n + z * hcarry[i];
        bf16 hv = (bf16)hn;
        hcarry[i] = (float)hv;
        pb[i * Hd] = hv;
      }
      if (t < Td - 1) barrier_fast(rg, cg, (unsigned)(t + 2));
    }
  } else {
    group_barrier(rg, cg, 2u);  // h0 complete (L3 scope)
    for (int t = 0; t < Td; t++) {
      bf16x8 a[16];
      const char* Ap = (const char*)&g_hbuf[t][arow][ksub];
      LDA16(a, Ap);

      f32x4 acc[4];
#pragma unroll
      for (int f = 0; f < 4; f++) {
        float bv = (t == 0) ? b0v[f] : b1v[f];
        acc[f] = (f32x4){bv, bv, bv, bv};
      }
      if (t == 0) {
        wait_vm0(); __builtin_amdgcn_sched_barrier(0);
#pragma unroll
        for (int k0 = 0; k0 < 16; k0++)
#pragma unroll
          for (int f = 0; f < 4; f++) {
            bf16x8 b = *(const bf16x8*)&g_wt0[colb + f * 16 + m][k0 * 32 + ksub];
            acc[f] = __builtin_amdgcn_mfma_f32_16x16x32_bf16(a[k0], b, acc[f], 0, 0, 0);
          }
      } else {
        wait_vm8(); __builtin_amdgcn_sched_barrier(0);
#pragma unroll
        for (int k0 = 0; k0 < 8; k0++)
#pragma unroll
          for (int f = 0; f < 4; f++)
            acc[f] = __builtin_amdgcn_mfma_f32_16x16x32_bf16(a[k0], Bw[f * 16 + k0], acc[f], 0, 0, 0);
        wait_vm0(); __builtin_amdgcn_sched_barrier(0);
#pragma unroll
        for (int k0 = 8; k0 < 16; k0++)
#pragma unroll
          for (int f = 0; f < 4; f++)
            acc[f] = __builtin_amdgcn_mfma_f32_16x16x32_bf16(a[k0], Bw[f * 16 + k0], acc[f], 0, 0, 0);
      }

      char* pb = (char*)&g_hbuf[t + 1][orow][hcol];
      unsigned short us[4];
#pragma unroll
      for (int i = 0; i < 4; i++) {
        float r = sigmoidf_(acc[0][i]);
        float z = sigmoidf_(acc[1][i]);
        float n = tanhf_(acc[2][i] + r * acc[3][i]);
        float hn = (1.f - z) * n + z * hcarry[i];
        bf16 hv = (bf16)hn;
        hcarry[i] = (float)hv;
        us[i] = __builtin_bit_cast(unsigned short, hv);
      }
      st_u16_cohere<0>(pb, us[0]);    st_u16_cohere<1024>(pb, us[1]);
      st_u16_cohere<2048>(pb, us[2]); st_u16_cohere<3072>(pb, us[3]);

      if (t < Td - 1) group_barrier(rg, cg, (unsigned)(t + 3));
    }
  }
  wait_vm0();  // h[200] stores complete before kernel end (end-of-kernel release handles visibility)
}

// ---------- projection: out[b][v][t] = sum_k h[t+1][b][k] * w_proj[k][v] + b_proj[v] ----------
// 256-thread blocks, grid (512,4): wave w handles t-tile by*4+w. Plain cached
// loads (inter-kernel visibility guaranteed by kernel-boundary coherence).
__global__ __launch_bounds__(256) void k_proj(const float* b_proj, float* out) {
  int b = blockIdx.x;
  int w = threadIdx.x >> 6, l = threadIdx.x & 63;
  int tt = blockIdx.y * 4 + w;
  if (tt > 12) return;
  int m = l & 15, ksub = (l >> 4) * 8;
  int tcol = tt * 16 + m;
  int trow = (tcol < Td ? tcol : Td - 1) + 1;  // clamp pad cols (masked on store)

  f32x4 acc[7];
#pragma unroll
  for (int f = 0; f < 7; f++)
#pragma unroll
    for (int i = 0; i < 4; i++) {
      int v = f * 16 + (l >> 4) * 4 + i;
      acc[f][i] = (v < Vd) ? b_proj[v] : 0.f;
    }

  bf16x8 bb[16];
  const bf16* Bp = &g_hbuf[trow][b][ksub];
#pragma unroll
  for (int k0 = 0; k0 < 16; k0++) bb[k0] = *(const bf16x8*)(Bp + k0 * 32);

#pragma unroll
  for (int k0 = 0; k0 < 16; k0++)
#pragma unroll
    for (int f = 0; f < 7; f++) {
      bf16x8 afrag = *(const bf16x8*)&g_wprojt[f * 16 + m][k0 * 32 + ksub];
      acc[f] = __builtin_amdgcn_mfma_f32_16x16x32_bf16(afrag, bb[k0], acc[f], 0, 0, 0);
    }

  if (tcol < Td) {
#pragma unroll
    for (int f = 0; f < 7; f++)
#pragma unroll
      for (int i = 0; i < 4; i++) {
        int v = f * 16 + (l >> 4) * 4 + i;
        if (v < Vd) out[((size_t)b * Vd + v) * Td + tcol] = acc[f][i];
      }
  }
}

// ---------- launch ----------
extern "C" void kernel_launch(void* const* d_in, const int* in_sizes, int n_in,
                              void* d_out, int out_size, void* d_ws, size_t ws_size,
                              hipStream_t stream) {
  const float* feat   = (const float*)d_in[0];
  const float* w_hp   = (const float*)d_in[1];
  const float* b_hp   = (const float*)d_in[2];
  const float* embed  = (const float*)d_in[3];
  const float* w_ih   = (const float*)d_in[4];
  const float* w_hh   = (const float*)d_in[5];
  const float* b_ih   = (const float*)d_in[6];
  const float* b_hh   = (const float*)d_in[7];
  const float* w_proj = (const float*)d_in[8];
  const float* b_proj = (const float*)d_in[9];
  float* out = (float*)d_out;

  hipLaunchKernelGGL(k_conv_feat, dim3((Bsz * FEAT) / 256), dim3(256), 0, stream, feat);
  hipLaunchKernelGGL(k_gi0, dim3(3 * Hd), dim3(64), 0, stream, embed, w_ih, b_ih);
  hipLaunchKernelGGL(k_build_wt1, dim3(Gd), dim3(256), 0, stream, w_ih, w_hh, b_ih, b_hh);
  hipLaunchKernelGGL(k_build_wt0, dim3(Gd), dim3(256), 0, stream, w_hh, b_hh);
  hipLaunchKernelGGL(k_build_whpt, dim3(Hd), dim3(256), 0, stream, w_hp);
  hipLaunchKernelGGL(k_build_wprojt, dim3(112), dim3(256), 0, stream, w_proj);
  hipLaunchKernelGGL(k_gru_seq, dim3(256), dim3(256), 0, stream, b_hp);
  hipLaunchKernelGGL(k_proj, dim3(Bsz, 4), dim3(256), 0, stream, b_proj, out);
}

// Round 6
// 1034.047 us; speedup vs baseline: 123.5171x; 1.1589x over previous
//
#include <hip/hip_runtime.h>

#define Bsz  512
#define FEAT 2048
#define Hd   512
#define Vd   100
#define Td   200
#define Gd   2048   // 4*H interleaved gate columns: per 16-col group [r|z|i_n|h_n]

typedef __bf16 bf16;
typedef __bf16 bf16x8 __attribute__((ext_vector_type(8)));
typedef float  f32x4  __attribute__((ext_vector_type(4)));

// Static device storage. Rewritten every launch -> deterministic across replays.
__device__ bf16  g_hbuf[Td + 1][Bsz][Hd];   // h chain: [0]=h0, [t+1]=output of step t
__device__ bf16  g_wt0[Gd][Hd];             // step-0 weights   [gatecol][k]
__device__ bf16  g_wt1[Gd][Hd];             // steps>=1 weights [gatecol][k]
__device__ float g_bias0[Gd];
__device__ float g_bias1[Gd];
__device__ bf16  g_featbf[Bsz][FEAT];
__device__ bf16  g_whpt[Hd][FEAT];          // w_hp transposed: [n][k]
__device__ bf16  g_wprojt[112][Hd];         // w_proj transposed+padded: [v][k]
__device__ float g_gi0[3 * Hd];             // embed[SOS] @ w_ih.T + b_ih
__device__ unsigned g_flags[8][32];         // [rowgroup][colgroup] L3-scope phase flags (slow path + publish)
__device__ unsigned g_bar[8][32];           // [rowgroup][0] = fast-path arrival counter (256B apart)
__device__ unsigned g_xcd[256];             // published XCC_ID per block

// ---------- device-coherent (L3, sc0 sc1) helpers — slow path ----------
template <int OFF>
__device__ __forceinline__ bf16x8 ld_b16x8_cohere(const void* p) {
  bf16x8 r;
  asm volatile("global_load_dwordx4 %0, %1, off offset:%2 sc0 sc1"
               : "=&v"(r) : "v"(p), "i"(OFF) : "memory");
  return r;
}
template <int OFF>
__device__ __forceinline__ void st_u16_cohere(void* p, unsigned short v) {
  asm volatile("global_store_short %0, %1, off offset:%2 sc0 sc1"
               :: "v"(p), "v"(v), "i"(OFF) : "memory");
}
__device__ __forceinline__ void st_u32_cohere(void* p, unsigned v) {
  asm volatile("global_store_dword %0, %1, off sc0 sc1" :: "v"(p), "v"(v) : "memory");
}
__device__ __forceinline__ unsigned ld_u32_cohere(const void* p) {
  unsigned r;
  asm volatile("global_load_dword %0, %1, off sc0 sc1\n\ts_waitcnt vmcnt(0)"
               : "=&v"(r) : "v"(p) : "memory");
  return r;
}
// ---------- L2-atomic helpers — fast path ----------
// LESSON (round 4): plain/sc0 loads can spin forever on L1-stale flag lines;
// only an atomic RMW is architecturally guaranteed to read L2.
__device__ __forceinline__ unsigned atomic_rd_l2(unsigned* p) {      // RMW at L2: L1-proof read
  unsigned r;
  asm volatile("global_atomic_add %0, %1, %2, off sc0\n\ts_waitcnt vmcnt(0)"
               : "=&v"(r) : "v"(p), "v"(0u) : "memory");
  return r;
}
__device__ __forceinline__ void atomic_inc_l2(unsigned* p) {         // no-return add at L2
  asm volatile("global_atomic_add %0, %1, off" :: "v"(p), "v"(1u) : "memory");
}
// Line prefetch into L2: no-return atomic add of 0. Idempotent, byte-disjoint
// with the later partial-line stores, does not allocate into L1. Converts the
// exposed store-RFO (~900cy HBM line fetch) into overlapped latency.
__device__ __forceinline__ void atomic_pf(void* p) {
  asm volatile("global_atomic_add %0, %1, off" :: "v"(p), "v"(0u) : "memory");
}
__device__ __forceinline__ void wait_vm0() { asm volatile("s_waitcnt vmcnt(0)" ::: "memory"); }
__device__ __forceinline__ void wait_vm8() { asm volatile("s_waitcnt vmcnt(8)" ::: "memory"); }

#define LDA16(arr, base) do {                                                   \
  arr[0]  = ld_b16x8_cohere<0>(base);   arr[1]  = ld_b16x8_cohere<64>(base);    \
  arr[2]  = ld_b16x8_cohere<128>(base); arr[3]  = ld_b16x8_cohere<192>(base);   \
  arr[4]  = ld_b16x8_cohere<256>(base); arr[5]  = ld_b16x8_cohere<320>(base);   \
  arr[6]  = ld_b16x8_cohere<384>(base); arr[7]  = ld_b16x8_cohere<448>(base);   \
  arr[8]  = ld_b16x8_cohere<512>(base); arr[9]  = ld_b16x8_cohere<576>(base);   \
  arr[10] = ld_b16x8_cohere<640>(base); arr[11] = ld_b16x8_cohere<704>(base);   \
  arr[12] = ld_b16x8_cohere<768>(base); arr[13] = ld_b16x8_cohere<832>(base);   \
  arr[14] = ld_b16x8_cohere<896>(base); arr[15] = ld_b16x8_cohere<960>(base);   \
} while (0)

__device__ __forceinline__ float sigmoidf_(float x) {
  x = fminf(fmaxf(x, -30.f), 30.f);
  return 1.f / (1.f + __expf(-x));
}
__device__ __forceinline__ float tanhf_(float x) {
  x = fminf(fmaxf(x, -15.f), 15.f);
  float e = __expf(2.f * x);
  return (e - 1.f) / (e + 1.f);
}

// Slow-path / publish barrier: device scope through L3 (placement-independent).
__device__ __forceinline__ void group_barrier(int rg, int cg, unsigned phase) {
  wait_vm0();
  __syncthreads();
  if (threadIdx.x == 0) st_u32_cohere(&g_flags[rg][cg], phase);
  if (threadIdx.x < 64) {
    const unsigned* fp = &g_flags[rg][threadIdx.x & 31];
    while (ld_u32_cohere(fp) < phase) __builtin_amdgcn_s_sleep(1);
  }
  __syncthreads();
}

// Fast-path barrier v2: ONE arrival counter per row group at the shared XCD
// L2. Single-lane increment + single-lane poll (1 RMW per iteration instead of
// round 5's 32 serialized RMWs on one line). __syncthreads drains this wave
// group's h stores first (cheap: store lines were atomic-prefetched into L2).
__device__ __forceinline__ void barrier_fast2(unsigned* cnt, unsigned target) {
  wait_vm0();
  __syncthreads();
  if (threadIdx.x == 0) {
    atomic_inc_l2(cnt);
    while (atomic_rd_l2(cnt) < target) __builtin_amdgcn_s_sleep(1);
  }
  __syncthreads();
}

// ---------- prep kernels ----------

__global__ void k_conv_feat(const float* feat) {
  int i = blockIdx.x * 256 + threadIdx.x;
  if (i < Bsz * FEAT) ((bf16*)g_featbf)[i] = (bf16)feat[i];
  if (blockIdx.x == 0) {  // reset barrier/publish state each replay
    ((unsigned*)g_flags)[threadIdx.x] = 0u;
    ((unsigned*)g_bar)[threadIdx.x] = 0u;
    g_xcd[threadIdx.x] = 0xffffffffu;
  }
}

__global__ void k_gi0(const float* embed, const float* w_ih, const float* b_ih) {
  int j = blockIdx.x;
  const float* wr = w_ih + (size_t)j * Hd;
  float s = 0.f;
  for (int k = threadIdx.x; k < Hd; k += 64) s += embed[k] * wr[k];
#pragma unroll
  for (int off = 32; off > 0; off >>= 1) s += __shfl_down(s, off);
  if (threadIdx.x == 0) g_gi0[j] = s + b_ih[j];
}

// gate col c: group g=c/64 (16 h-cols), f=(c>>4)&3 in {r,z,i_n,h_n}, j = g*16 + (c&15)
__global__ void k_build_wt1(const float* w_ih, const float* w_hh,
                            const float* b_ih, const float* b_hh) {
  int c = blockIdx.x;
  int j = (c >> 6) * 16 + (c & 15);
  int f = (c >> 4) & 3;
  const float* s1 = nullptr; const float* s2 = nullptr; float bias;
  if (f == 0)      { s1 = w_ih + (size_t)j * Hd;            s2 = w_hh + (size_t)j * Hd;            bias = b_ih[j] + b_hh[j]; }
  else if (f == 1) { s1 = w_ih + (size_t)(Hd + j) * Hd;     s2 = w_hh + (size_t)(Hd + j) * Hd;     bias = b_ih[Hd + j] + b_hh[Hd + j]; }
  else if (f == 2) { s1 = w_ih + (size_t)(2 * Hd + j) * Hd;                                        bias = b_ih[2 * Hd + j]; }
  else             { s1 = w_hh + (size_t)(2 * Hd + j) * Hd;                                        bias = b_hh[2 * Hd + j]; }
  for (int k = threadIdx.x; k < Hd; k += 256) {
    float v = s1[k] + (s2 ? s2[k] : 0.f);
    g_wt1[c][k] = (bf16)v;
  }
  if (threadIdx.x == 0) g_bias1[c] = bias;
}

__global__ void k_build_wt0(const float* w_hh, const float* b_hh) {
  int c = blockIdx.x;
  int j = (c >> 6) * 16 + (c & 15);
  int f = (c >> 4) & 3;
  const float* s1 = nullptr; float bias;
  if (f == 0)      { s1 = w_hh + (size_t)j * Hd;            bias = g_gi0[j] + b_hh[j]; }
  else if (f == 1) { s1 = w_hh + (size_t)(Hd + j) * Hd;     bias = g_gi0[Hd + j] + b_hh[Hd + j]; }
  else if (f == 2) {                                        bias = g_gi0[2 * Hd + j]; }
  else             { s1 = w_hh + (size_t)(2 * Hd + j) * Hd; bias = b_hh[2 * Hd + j]; }
  for (int k = threadIdx.x; k < Hd; k += 256)
    g_wt0[c][k] = (bf16)(s1 ? s1[k] : 0.f);
  if (threadIdx.x == 0) g_bias0[c] = bias;
}

__global__ void k_build_whpt(const float* w_hp) {
  int n = blockIdx.x;
  for (int k = threadIdx.x; k < FEAT; k += 256)
    g_whpt[n][k] = (bf16)w_hp[(size_t)k * Hd + n];
}

__global__ void k_build_wprojt(const float* w_proj) {
  int v = blockIdx.x;  // 0..111
  for (int k = threadIdx.x; k < Hd; k += 256)
    g_wprojt[v][k] = (bf16)(v < Vd ? w_proj[(size_t)k * Vd + v] : 0.f);
}

// ---------- persistent kernel: h0 + all 200 GRU steps ----------
// 256 blocks (1/CU), 256 threads. rg=bid&7: 64-row batch group (same XCD under
// round-robin dispatch); cg=bid>>3: 16 h-col group. Steps>=1 weights persist in
// VGPR/AGPR. Runtime XCC_ID check selects L2-scope (fast) or L3-scope (slow)
// h exchange; correctness never depends on placement (G16).
__global__ __launch_bounds__(256, 1) void k_gru_seq(const float* b_hp) {
  const int bid = blockIdx.x;
  const int rg = bid & 7;
  const int cg = bid >> 3;
  const int w = threadIdx.x >> 6, l = threadIdx.x & 63;
  const int m = l & 15;
  const int ksub = (l >> 4) * 8;
  const int colb = cg * 64;
  const int arow = rg * 64 + w * 16 + m;
  const int orow = rg * 64 + w * 16 + (l >> 4) * 4;
  const int hcol = cg * 16 + m;
  __shared__ int s_fast;

  // persistent B-fragments for steps >= 1 (4 gates x 16 k-chunks)
  bf16x8 Bw[64];
#pragma unroll
  for (int f = 0; f < 4; f++)
#pragma unroll
    for (int k0 = 0; k0 < 16; k0++)
      Bw[f * 16 + k0] = *(const bf16x8*)&g_wt1[colb + f * 16 + m][k0 * 32 + ksub];

  float b0v[4], b1v[4];
#pragma unroll
  for (int f = 0; f < 4; f++) {
    b0v[f] = g_bias0[colb + f * 16 + m];
    b1v[f] = g_bias1[colb + f * 16 + m];
  }

  // ---- publish XCC_ID, then decide fast/slow per row group ----
  unsigned xcc;
  asm volatile("s_getreg_b32 %0, hwreg(HW_REG_XCC_ID)" : "=s"(xcc));
  if (threadIdx.x == 0) st_u32_cohere(&g_xcd[bid], xcc);
  group_barrier(rg, cg, 1u);  // publish complete (L3 scope)
  if (threadIdx.x < 64) {
    unsigned peer = ld_u32_cohere(&g_xcd[rg + 8 * (threadIdx.x & 31)]);
    unsigned long long bal = __ballot(peer == xcc);
    if (threadIdx.x == 0) s_fast = (bal == ~0ull) ? 1 : 0;
  }
  __syncthreads();
  const bool fast = (s_fast != 0);

  // ---- h0 = feat @ w_hp + b_hp ----
  float hcarry[4];
  {
    f32x4 acc = {0.f, 0.f, 0.f, 0.f};
#pragma unroll 4
    for (int k0 = 0; k0 < FEAT; k0 += 32) {
      bf16x8 a = *(const bf16x8*)&g_featbf[arow][k0 + ksub];
      bf16x8 b = *(const bf16x8*)&g_whpt[hcol][k0 + ksub];
      acc = __builtin_amdgcn_mfma_f32_16x16x32_bf16(a, b, acc, 0, 0, 0);
    }
    float bhp = b_hp[hcol];
    bf16* pb = &g_hbuf[0][orow][hcol];
    unsigned short us[4];
#pragma unroll
    for (int i = 0; i < 4; i++) {
      bf16 hv = (bf16)(acc[i] + bhp);
      hcarry[i] = (float)hv;
      us[i] = __builtin_bit_cast(unsigned short, hv);
    }
    if (fast) {
#pragma unroll
      for (int i = 0; i < 4; i++) pb[i * Hd] = __builtin_bit_cast(bf16, us[i]);
    } else {
      char* pc = (char*)pb;
      st_u16_cohere<0>(pc, us[0]);    st_u16_cohere<1024>(pc, us[1]);
      st_u16_cohere<2048>(pc, us[2]); st_u16_cohere<3072>(pc, us[3]);
    }
  }

  if (fast) {
    unsigned* cnt = &g_bar[rg][0];
    barrier_fast2(cnt, 32u * 1);  // h0 complete (L2 scope)

    for (int t = 0; t < Td; t++) {
      // A-slice of h[t] (plain loads: L2-hot, written last step on this XCD)
      bf16x8 a[16];
      const bf16* Ap = &g_hbuf[t][arow][ksub];
#pragma unroll
      for (int k0 = 0; k0 < 16; k0++) a[k0] = *(const bf16x8*)(Ap + k0 * 32);

      // prefetch the lines this block will store (h[t+1], 64 rows x 32B):
      // RFO overlaps the MFMA+epilogue below instead of stalling the barrier.
      if (threadIdx.x < 64) atomic_pf((void*)&g_hbuf[t + 1][rg * 64 + threadIdx.x][cg * 16]);

      f32x4 acc[4], acc2[4];
#pragma unroll
      for (int f = 0; f < 4; f++) {
        float bv = (t == 0) ? b0v[f] : b1v[f];
        acc[f]  = (f32x4){bv, bv, bv, bv};
        acc2[f] = (f32x4){0.f, 0.f, 0.f, 0.f};
      }
      if (t == 0) {  // step-0 weight set streamed from L2 once
#pragma unroll
        for (int k0 = 0; k0 < 8; k0++)
#pragma unroll
          for (int f = 0; f < 4; f++) {
            bf16x8 b = *(const bf16x8*)&g_wt0[colb + f * 16 + m][k0 * 32 + ksub];
            acc[f] = __builtin_amdgcn_mfma_f32_16x16x32_bf16(a[k0], b, acc[f], 0, 0, 0);
          }
#pragma unroll
        for (int k0 = 8; k0 < 16; k0++)
#pragma unroll
          for (int f = 0; f < 4; f++) {
            bf16x8 b = *(const bf16x8*)&g_wt0[colb + f * 16 + m][k0 * 32 + ksub];
            acc2[f] = __builtin_amdgcn_mfma_f32_16x16x32_bf16(a[k0], b, acc2[f], 0, 0, 0);
          }
      } else {
        // two K-half accumulator chains (depth 8 each) for MFMA ILP
#pragma unroll
        for (int k0 = 0; k0 < 8; k0++)
#pragma unroll
          for (int f = 0; f < 4; f++)
            acc[f] = __builtin_amdgcn_mfma_f32_16x16x32_bf16(a[k0], Bw[f * 16 + k0], acc[f], 0, 0, 0);
#pragma unroll
        for (int k0 = 8; k0 < 16; k0++)
#pragma unroll
          for (int f = 0; f < 4; f++)
            acc2[f] = __builtin_amdgcn_mfma_f32_16x16x32_bf16(a[k0], Bw[f * 16 + k0], acc2[f], 0, 0, 0);
      }

      bf16* pb = &g_hbuf[t + 1][orow][hcol];
#pragma unroll
      for (int i = 0; i < 4; i++) {
        float r = sigmoidf_(acc[0][i] + acc2[0][i]);
        float z = sigmoidf_(acc[1][i] + acc2[1][i]);
        float n = tanhf_((acc[2][i] + acc2[2][i]) + r * (acc[3][i] + acc2[3][i]));
        float hn = (1.f - z) * n + z * hcarry[i];
        bf16 hv = (bf16)hn;
        hcarry[i] = (float)hv;
        pb[i * Hd] = hv;
      }
      if (t < Td - 1) barrier_fast2(cnt, 32u * (unsigned)(t + 2));
    }
  } else {
    group_barrier(rg, cg, 2u);  // h0 complete (L3 scope)
    for (int t = 0; t < Td; t++) {
      bf16x8 a[16];
      const char* Ap = (const char*)&g_hbuf[t][arow][ksub];
      LDA16(a, Ap);

      f32x4 acc[4];
#pragma unroll
      for (int f = 0; f < 4; f++) {
        float bv = (t == 0) ? b0v[f] : b1v[f];
        acc[f] = (f32x4){bv, bv, bv, bv};
      }
      if (t == 0) {
        wait_vm0(); __builtin_amdgcn_sched_barrier(0);
#pragma unroll
        for (int k0 = 0; k0 < 16; k0++)
#pragma unroll
          for (int f = 0; f < 4; f++) {
            bf16x8 b = *(const bf16x8*)&g_wt0[colb + f * 16 + m][k0 * 32 + ksub];
            acc[f] = __builtin_amdgcn_mfma_f32_16x16x32_bf16(a[k0], b, acc[f], 0, 0, 0);
          }
      } else {
        wait_vm8(); __builtin_amdgcn_sched_barrier(0);
#pragma unroll
        for (int k0 = 0; k0 < 8; k0++)
#pragma unroll
          for (int f = 0; f < 4; f++)
            acc[f] = __builtin_amdgcn_mfma_f32_16x16x32_bf16(a[k0], Bw[f * 16 + k0], acc[f], 0, 0, 0);
        wait_vm0(); __builtin_amdgcn_sched_barrier(0);
#pragma unroll
        for (int k0 = 8; k0 < 16; k0++)
#pragma unroll
          for (int f = 0; f < 4; f++)
            acc[f] = __builtin_amdgcn_mfma_f32_16x16x32_bf16(a[k0], Bw[f * 16 + k0], acc[f], 0, 0, 0);
      }

      char* pb = (char*)&g_hbuf[t + 1][orow][hcol];
      unsigned short us[4];
#pragma unroll
      for (int i = 0; i < 4; i++) {
        float r = sigmoidf_(acc[0][i]);
        float z = sigmoidf_(acc[1][i]);
        float n = tanhf_(acc[2][i] + r * acc[3][i]);
        float hn = (1.f - z) * n + z * hcarry[i];
        bf16 hv = (bf16)hn;
        hcarry[i] = (float)hv;
        us[i] = __builtin_bit_cast(unsigned short, hv);
      }
      st_u16_cohere<0>(pb, us[0]);    st_u16_cohere<1024>(pb, us[1]);
      st_u16_cohere<2048>(pb, us[2]); st_u16_cohere<3072>(pb, us[3]);

      if (t < Td - 1) group_barrier(rg, cg, (unsigned)(t + 3));
    }
  }
  wait_vm0();  // h[200] stores complete before kernel end (end-of-kernel release handles visibility)
}

// ---------- projection: out[b][v][t] = sum_k h[t+1][b][k] * w_proj[k][v] + b_proj[v] ----------
// 256-thread blocks, grid (512,4): wave w handles t-tile by*4+w. Plain cached
// loads (inter-kernel visibility guaranteed by kernel-boundary coherence).
__global__ __launch_bounds__(256) void k_proj(const float* b_proj, float* out) {
  int b = blockIdx.x;
  int w = threadIdx.x >> 6, l = threadIdx.x & 63;
  int tt = blockIdx.y * 4 + w;
  if (tt > 12) return;
  int m = l & 15, ksub = (l >> 4) * 8;
  int tcol = tt * 16 + m;
  int trow = (tcol < Td ? tcol : Td - 1) + 1;  // clamp pad cols (masked on store)

  f32x4 acc[7];
#pragma unroll
  for (int f = 0; f < 7; f++)
#pragma unroll
    for (int i = 0; i < 4; i++) {
      int v = f * 16 + (l >> 4) * 4 + i;
      acc[f][i] = (v < Vd) ? b_proj[v] : 0.f;
    }

  bf16x8 bb[16];
  const bf16* Bp = &g_hbuf[trow][b][ksub];
#pragma unroll
  for (int k0 = 0; k0 < 16; k0++) bb[k0] = *(const bf16x8*)(Bp + k0 * 32);

#pragma unroll
  for (int k0 = 0; k0 < 16; k0++)
#pragma unroll
    for (int f = 0; f < 7; f++) {
      bf16x8 afrag = *(const bf16x8*)&g_wprojt[f * 16 + m][k0 * 32 + ksub];
      acc[f] = __builtin_amdgcn_mfma_f32_16x16x32_bf16(afrag, bb[k0], acc[f], 0, 0, 0);
    }

  if (tcol < Td) {
#pragma unroll
    for (int f = 0; f < 7; f++)
#pragma unroll
      for (int i = 0; i < 4; i++) {
        int v = f * 16 + (l >> 4) * 4 + i;
        if (v < Vd) out[((size_t)b * Vd + v) * Td + tcol] = acc[f][i];
      }
  }
}

// ---------- launch ----------
extern "C" void kernel_launch(void* const* d_in, const int* in_sizes, int n_in,
                              void* d_out, int out_size, void* d_ws, size_t ws_size,
                              hipStream_t stream) {
  const float* feat   = (const float*)d_in[0];
  const float* w_hp   = (const float*)d_in[1];
  const float* b_hp   = (const float*)d_in[2];
  const float* embed  = (const float*)d_in[3];
  const float* w_ih   = (const float*)d_in[4];
  const float* w_hh   = (const float*)d_in[5];
  const float* b_ih   = (const float*)d_in[6];
  const float* b_hh   = (const float*)d_in[7];
  const float* w_proj = (const float*)d_in[8];
  const float* b_proj = (const float*)d_in[9];
  float* out = (float*)d_out;

  hipLaunchKernelGGL(k_conv_feat, dim3((Bsz * FEAT) / 256), dim3(256), 0, stream, feat);
  hipLaunchKernelGGL(k_gi0, dim3(3 * Hd), dim3(64), 0, stream, embed, w_ih, b_ih);
  hipLaunchKernelGGL(k_build_wt1, dim3(Gd), dim3(256), 0, stream, w_ih, w_hh, b_ih, b_hh);
  hipLaunchKernelGGL(k_build_wt0, dim3(Gd), dim3(256), 0, stream, w_hh, b_hh);
  hipLaunchKernelGGL(k_build_whpt, dim3(Hd), dim3(256), 0, stream, w_hp);
  hipLaunchKernelGGL(k_build_wprojt, dim3(112), dim3(256), 0, stream, w_proj);
  hipLaunchKernelGGL(k_gru_seq, dim3(256), dim3(256), 0, stream, b_hp);
  hipLaunchKernelGGL(k_proj, dim3(Bsz, 4), dim3(256), 0, stream, b_proj, out);
}